// Round 10
// baseline (89.213 us; speedup 1.0000x reference)
//
#include <hip/hip_runtime.h>

#define NQ 10
#define NG 4
#define QD 6
#define NBATCH 1024

// 2^10 = 1024 amps; 64 lanes x 16 amps/lane. R10: one WAVE = one REAL
// COMPONENT (re or im) of one circuit — all post-init gates are real
// (tangent-form RY + CZ sign flips), so re/im evolve independently.
// 8192 waves -> 8 waves/SIMD (R9 was grid-capped at 4). Init (complex
// product state) is duplicated in both waves; the only coupling is the
// final 10 partial sums via 128 B of LDS.
// Flat index i: bit p (LSB) <-> wire q = 9-p (wire 0 = MSB, PennyLane order).
// Layout A: reg bits 0..3 <- amp bits 0..3, lane bits 0..5 <- amp bits 4..9.
// Layout B (after one transpose set): reg2<->lane4, reg3<->lane5 swapped.
// Alternating-layout trick: each layer does ONE transpose set (A->B or
// B->A) instead of in+out, halving permlane traffic. CZ masks precomputed
// for both layouts via parity decomposition (4 regs each).

typedef unsigned u2v __attribute__((ext_vector_type(2)));

// ---------- DPP helpers ----------
template<int CTRL, int RM, int BM, bool BC>
__device__ __forceinline__ float dppmov(float x) {
    return __int_as_float(__builtin_amdgcn_update_dpp(
        0, __float_as_int(x), CTRL, RM, BM, BC));
}
template<int CTRL>
__device__ __forceinline__ float dpp1(float x) { return dppmov<CTRL,0xF,0xF,true>(x); }
// xor1 = quad_perm{1,0,3,2}=0xB1; xor2 = quad_perm{2,3,0,1}=0x4E;
// xor4 = 0x141(row_half_mirror,^7) then 0x1B(quad rev,^3); xor8 = row_ror:8=0x128.

struct FX1 { static __device__ __forceinline__ float f(float x){ return dpp1<0xB1>(x); } };
struct FX2 { static __device__ __forceinline__ float f(float x){ return dpp1<0x4E>(x); } };
struct FX4 { static __device__ __forceinline__ float f(float x){ return dpp1<0x1B>(dpp1<0x141>(x)); } };
struct FX8 { static __device__ __forceinline__ float f(float x){ return dpp1<0x128>(x); } };
struct FX16 {
    static __device__ __forceinline__ float f(float x){
        return __int_as_float(__builtin_amdgcn_ds_swizzle(__float_as_int(x), 0x401F));
    }
};
struct FX32 {
    static __device__ __forceinline__ float f(float x){ return __shfl_xor(x, 32, 64); }
};

__device__ __forceinline__ float rlane(float v, int idx) {
    return __int_as_float(__builtin_amdgcn_readlane(__float_as_int(v), idx));
}

// ---------- gfx950 permlane swap transposes (validated R6/R8/R9) ----------
#if __has_builtin(__builtin_amdgcn_permlane32_swap) && __has_builtin(__builtin_amdgcn_permlane16_swap)
#define HAVE_SWAP 1
__device__ __forceinline__ void plswap32(float &a, float &b) {
    u2v r = __builtin_amdgcn_permlane32_swap(__float_as_uint(a), __float_as_uint(b), false, false);
    a = __uint_as_float(r.x); b = __uint_as_float(r.y);
}
__device__ __forceinline__ void plswap16(float &a, float &b) {
    u2v r = __builtin_amdgcn_permlane16_swap(__float_as_uint(a), __float_as_uint(b), false, false);
    a = __uint_as_float(r.x); b = __uint_as_float(r.y);
}
// one transpose set: lane5<->reg3, lane4<->reg2 (involution, toggles A<->B)
__device__ __forceinline__ void tr_set(float (&s)[16]) {
#pragma unroll
    for (int j = 0; j < 8; ++j) plswap32(s[j], s[j + 8]);
#pragma unroll
    for (int jj = 0; jj < 8; ++jj) {
        const int j = (jj & 3) | ((jj >> 2) << 3);   // 0,1,2,3,8,9,10,11
        plswap16(s[j], s[j + 4]);
    }
}
#else
#define HAVE_SWAP 0
#endif

// wave-wide sum broadcast (validated R3..R9)
__device__ __forceinline__ float wave_reduce(float x) {
    x += dppmov<0x111,0xF,0xF,true >(x);
    x += dppmov<0x112,0xF,0xF,true >(x);
    x += dppmov<0x114,0xF,0xF,true >(x);
    x += dppmov<0x118,0xF,0xF,true >(x);
    x += dppmov<0x142,0xA,0xF,false>(x);
    x += dppmov<0x143,0xC,0xF,false>(x);
    return __int_as_float(__builtin_amdgcn_readlane(__float_as_int(x), 63));
}

// wave-wide product (R9-validated)
__device__ __forceinline__ float wave_product(float x) {
    x *= dpp1<0xB1>(x);
    x *= dpp1<0x4E>(x);
    x *= dpp1<0x1B>(dpp1<0x141>(x));
    x *= dpp1<0x128>(x);
    x *= FX16::f(x);
    x *= FX32::f(x);
    return x;
}

// (I - t*J) intra-register pair (R9-validated)
template<int M>
__device__ __forceinline__ void intra_rot_t(float (&s)[16], float t) {
#pragma unroll
    for (int j = 0; j < 16; ++j)
        if ((j & M) == 0) {
            const int k = j | M;
            float v0 = s[j], v1 = s[k];
            s[j] = fmaf(-t, v1, v0);
            s[k] = fmaf( t, v0, v1);
        }
}

// (I - t*J) cross-lane on one array (sign convention validated R1..R9)
template<class PF, int LM>
__device__ __forceinline__ void cross_rot_t(float (&s)[16], float t, int lane) {
    const float sv = (lane & LM) ? t : -t;
#pragma unroll
    for (int j = 0; j < 16; ++j)
        s[j] = fmaf(PF::f(s[j]), sv, s[j]);
}

template<class PF>
__device__ __forceinline__ float cross_exp(const float (&s)[16]) {
    float a = 0.f;
#pragma unroll
    for (int j = 0; j < 16; ++j)
        a = fmaf(PF::f(s[j]), s[j], a);
    return a;
}

template<int M>
__device__ __forceinline__ float intra_exp(const float (&s)[16]) {
    float a = 0.f;
#pragma unroll
    for (int j = 0; j < 16; ++j)
        a += s[j] * s[j ^ M];
    return a;
}

__global__ __launch_bounds__(256, 2) void qsim_kernel(
    const float* __restrict__ noise,     // (NBATCH, NQ)
    const float* __restrict__ qp,        // (NG, QD, NQ)
    float* __restrict__ out)             // (NBATCH, NG*NQ)
{
    __shared__ float partlds[2][16];     // re-wave expectation partials

    const int wave = threadIdx.x >> 6;
    const int lane = threadIdx.x & 63;
    const int pc   = wave >> 1;                       // circuit within block
    const int comp = wave & 1;                        // 0 = re, 1 = im
    const int g    = blockIdx.x & 3;                  // block-uniform
    const int b    = (blockIdx.x >> 2) * 2 + pc;      // batch index

    // ---- weights: lane-parallel sincos once; t = tan, scale2 = prod(c)^2 ----
    float wt, scale2;
    {
        const int widx = (lane < QD * NQ) ? lane : 0;
        float sv, cv;
        __sincosf(0.5f * qp[g * (QD * NQ) + widx], &sv, &cv);
        wt = sv / cv;
        float cvc = (lane < QD * NQ) ? cv : 1.0f;
        float p = wave_product(cvc);
        scale2 = p * p;
    }

    // ---- init: complex product state RX(t)RY(t)|0>, duplicated per wave;
    //      this wave keeps only its component ----
    float s[16];
    {
        float nc[NQ], ns[NQ];
#pragma unroll
        for (int q = 0; q < NQ; ++q)
            __sincosf(0.5f * noise[b * NQ + q], &ns[q], &nc[q]);

        auto facr = [&](int q, int bit) { return bit ? nc[q]*ns[q] : nc[q]*nc[q]; };
        auto faci = [&](int q, int bit) { return bit ? -nc[q]*ns[q] : -ns[q]*ns[q]; };

        float hr = 1.f, hi = 0.f;
#pragma unroll
        for (int p = 4; p <= 9; ++p) {
            const int q = NQ - 1 - p, bit = (lane >> (p - 4)) & 1;
            float fr = facr(q, bit), fi = faci(q, bit);
            float tr = hr * fr - hi * fi;
            float ti = hr * fi + hi * fr;
            hr = tr; hi = ti;
        }
        float t01r[4], t01i[4], t23r[4], t23i[4];
#pragma unroll
        for (int a = 0; a < 4; ++a) {
            float f9r = facr(9, a & 1), f9i = faci(9, a & 1);
            float f8r = facr(8, (a >> 1) & 1), f8i = faci(8, (a >> 1) & 1);
            t01r[a] = f9r * f8r - f9i * f8i;
            t01i[a] = f9r * f8i + f9i * f8r;
            float f7r = facr(7, a & 1), f7i = faci(7, a & 1);
            float f6r = facr(6, (a >> 1) & 1), f6i = faci(6, (a >> 1) & 1);
            t23r[a] = f7r * f6r - f7i * f6i;
            t23i[a] = f7r * f6i + f7i * f6r;
        }
        float prer[4], prei[4];
#pragma unroll
        for (int a = 0; a < 4; ++a) {
            prer[a] = hr * t01r[a] - hi * t01i[a];
            prei[a] = hr * t01i[a] + hi * t01r[a];
        }
#pragma unroll
        for (int j = 0; j < 16; ++j) {
            float rr = prer[j & 3] * t23r[j >> 2] - prei[j & 3] * t23i[j >> 2];
            float ii = prer[j & 3] * t23i[j >> 2] + prei[j & 3] * t23r[j >> 2];
            s[j] = comp ? ii : rr;
        }
    }

    // ---- CZ sign masks, both layouts (parity decomposition; A validated R9) --
    // Layout A: amp bits b0..b3 = j0..j3, b4..b9 = l0..l5.
    unsigned aE, aO;
    {
        unsigned parA = (unsigned)(__popc(lane & (lane >> 1)) & 1) << 31;
        aE = parA;                                     // j < 8
        aO = parA ^ ((unsigned)(lane & 1) << 31);      // j >= 8 (pair j3,l0)
    }
    // Layout B: amp bits b0=j0,b1=j1,b2=l4,b3=l5,b4=l0,b5=l1,b6=l2,b7=l3,b8=j2,b9=j3.
    unsigned b00, b10, b01, b11;
    {
        const unsigned l0 = lane & 1, l1 = (lane >> 1) & 1, l2 = (lane >> 2) & 1,
                       l3 = (lane >> 3) & 1, l4 = (lane >> 4) & 1, l5 = (lane >> 5) & 1;
        unsigned parB = ((l4 & l5) ^ (l5 & l0) ^ (l0 & l1) ^ (l1 & l2) ^ (l2 & l3)) << 31;
        b00 = parB;                                    // (j1,j2) = (0,0)
        b10 = parB ^ (l4 << 31);                       // j1 pairs with l4
        b01 = parB ^ (l3 << 31);                       // j2 pairs with l3
        b11 = parB ^ ((l4 ^ l3) << 31);
    }
    auto czA = [&](float (&v)[16]) {
#pragma unroll
        for (int j = 0; j < 16; ++j) {
            const bool jp = (__popc(j & (j >> 1)) & 1) != 0;         // compile-time
            const unsigned base = (j & 8) ? aO : aE;
            const unsigned m = jp ? (base ^ 0x80000000u) : base;
            v[j] = __uint_as_float(__float_as_uint(v[j]) ^ m);
        }
    };
    auto czB = [&](float (&v)[16]) {
#pragma unroll
        for (int j = 0; j < 16; ++j) {
            const int j0 = j & 1, j1 = (j >> 1) & 1, j2 = (j >> 2) & 1, j3 = (j >> 3) & 1;
            const bool pj = ((j0 & j1) ^ (j2 & j3)) != 0;            // compile-time
            const unsigned base = j1 ? (j2 ? b11 : b10) : (j2 ? b01 : b00);
            const unsigned m = pj ? (base ^ 0x80000000u) : base;
            v[j] = __uint_as_float(__float_as_uint(v[j]) ^ m);
        }
    };

    // ---- QD layers: 3 x (A-layer, B-layer); one transpose set per layer ----
#if HAVE_SWAP
#pragma unroll 1
    for (int d = 0; d < QD / 2; ++d) {
        float t[2 * NQ];
#pragma unroll
        for (int q = 0; q < 2 * NQ; ++q) t[q] = rlane(wt, 2 * d * NQ + q);

        // ---- A-layer (state in layout A) ----
        intra_rot_t<1>(s, t[9]);                 // wire 9 (amp bit 0)
        intra_rot_t<2>(s, t[8]);
        intra_rot_t<4>(s, t[7]);
        intra_rot_t<8>(s, t[6]);
        cross_rot_t<FX1, 1>(s, t[5], lane);      // wires 5..2 (lane bits 0..3)
        cross_rot_t<FX2, 2>(s, t[4], lane);
        cross_rot_t<FX4, 4>(s, t[3], lane);
        cross_rot_t<FX8, 8>(s, t[2], lane);
        tr_set(s);                               // -> layout B
        intra_rot_t<8>(s, t[0]);                 // wire 0 (amp bit 9 = reg 3)
        intra_rot_t<4>(s, t[1]);                 // wire 1 (amp bit 8 = reg 2)
        czB(s);

        // ---- B-layer (state in layout B) ----
        intra_rot_t<1>(s, t[NQ + 9]);            // wire 9 (amp bit 0)
        intra_rot_t<2>(s, t[NQ + 8]);
        intra_rot_t<8>(s, t[NQ + 0]);            // wire 0 (reg 3)
        intra_rot_t<4>(s, t[NQ + 1]);            // wire 1 (reg 2)
        cross_rot_t<FX1, 1>(s, t[NQ + 5], lane); // wires 5..2 unchanged in B
        cross_rot_t<FX2, 2>(s, t[NQ + 4], lane);
        cross_rot_t<FX4, 4>(s, t[NQ + 3], lane);
        cross_rot_t<FX8, 8>(s, t[NQ + 2], lane);
        tr_set(s);                               // -> layout A
        intra_rot_t<4>(s, t[NQ + 7]);            // wire 7 (amp bit 2 = reg 2)
        intra_rot_t<8>(s, t[NQ + 6]);            // wire 6 (amp bit 3 = reg 3)
        czA(s);
    }
#else
#pragma unroll 1
    for (int l = 0; l < QD; ++l) {
        float t[NQ];
#pragma unroll
        for (int q = 0; q < NQ; ++q) t[q] = rlane(wt, l * NQ + q);
        intra_rot_t<1>(s, t[9]);
        intra_rot_t<2>(s, t[8]);
        intra_rot_t<4>(s, t[7]);
        intra_rot_t<8>(s, t[6]);
        cross_rot_t<FX1, 1>(s, t[5], lane);
        cross_rot_t<FX2, 2>(s, t[4], lane);
        cross_rot_t<FX4, 4>(s, t[3], lane);
        cross_rot_t<FX8, 8>(s, t[2], lane);
        cross_rot_t<FX32,32>(s, t[0], lane);
        cross_rot_t<FX16,16>(s, t[1], lane);
        czA(s);
    }
#endif

    // ---- expectations: this component's partial sums (state in layout A) ----
    float myp = 0.f;
    {
        float e9 = wave_reduce(intra_exp<1>(s));
        float e8 = wave_reduce(intra_exp<2>(s));
        float e7 = wave_reduce(intra_exp<4>(s));
        float e6 = wave_reduce(intra_exp<8>(s));
        float e5 = wave_reduce(cross_exp<FX1>(s));
        float e4 = wave_reduce(cross_exp<FX2>(s));
        float e3 = wave_reduce(cross_exp<FX4>(s));
        float e2 = wave_reduce(cross_exp<FX8>(s));
        float e0, e1;
#if HAVE_SWAP
        tr_set(s);                               // -> layout B for wires 0,1
        e0 = wave_reduce(intra_exp<8>(s));
        e1 = wave_reduce(intra_exp<4>(s));
#else
        e0 = wave_reduce(cross_exp<FX32>(s));
        e1 = wave_reduce(cross_exp<FX16>(s));
#endif
        myp = (lane == 0) ? e0 : myp;
        myp = (lane == 1) ? e1 : myp;
        myp = (lane == 2) ? e2 : myp;
        myp = (lane == 3) ? e3 : myp;
        myp = (lane == 4) ? e4 : myp;
        myp = (lane == 5) ? e5 : myp;
        myp = (lane == 6) ? e6 : myp;
        myp = (lane == 7) ? e7 : myp;
        myp = (lane == 8) ? e8 : myp;
        myp = (lane == 9) ? e9 : myp;
    }

    // ---- couple re+im partials via LDS; im wave stores ----
    if (comp == 0 && lane < NQ) partlds[pc][lane] = myp;
    __syncthreads();
    if (comp == 1 && lane < NQ)
        out[b * (NG * NQ) + g * NQ + lane] = (myp + partlds[pc][lane]) * scale2;
}

extern "C" void kernel_launch(void* const* d_in, const int* in_sizes, int n_in,
                              void* d_out, int out_size, void* d_ws, size_t ws_size,
                              hipStream_t stream) {
    const float* noise = (const float*)d_in[0];   // (1024, 10) float32
    const float* qp    = (const float*)d_in[1];   // (4, 6, 10) float32
    float* out = (float*)d_out;                   // (1024, 40) float32

    const int nblocks = (NBATCH * NG) / 2;        // 2048 blocks x 4 waves
    qsim_kernel<<<nblocks, 256, 0, stream>>>(noise, qp, out);
}

// Round 12
// 85.091 us; speedup vs baseline: 1.0484x; 1.0484x over previous
//
#include <hip/hip_runtime.h>

#define NQ 10
#define NG 4
#define QD 6
#define NBATCH 1024
#define WPB 4   // waves per block; block = 4 batch samples of ONE generator

// 2^10 = 1024 amps; 64 lanes x 16 amps/lane, one circuit per wave (both
// re and im arrays: tangent-form layers are real, 16+16 state regs).
// Flat index i: bit p (LSB) <-> wire q = 9-p (wire 0 = MSB, PennyLane order).
// Layout A: reg bits 0..3 <- amp bits 0..3, lane bits 0..5 <- amp bits 4..9.
// Layout B: reg2<->lane4, reg3<->lane5 swapped (one tr_set toggles A<->B).
// R12 = R11 with the ds_swizzle pattern as a TEMPLATE parameter (the
// builtin requires a constant integer; R11 passed it as a runtime arg).
// Theory: row-crossing DPP/permlane cost ~3x plain VALU while the LDS pipe
// sits idle -> FX4/FX8 fetches moved to ds_swizzle (LDS pipe, overlaps
// VALU); FX1/FX2 stay quad_perm DPP. Alternating A/B layouts halve
// permlane transposes (R10-validated). tan-form + global scale (R9).

typedef unsigned u2v __attribute__((ext_vector_type(2)));

// ---------- DPP helpers ----------
template<int CTRL, int RM, int BM, bool BC>
__device__ __forceinline__ float dppmov(float x) {
    return __int_as_float(__builtin_amdgcn_update_dpp(
        0, __float_as_int(x), CTRL, RM, BM, BC));
}
template<int CTRL>
__device__ __forceinline__ float dpp1(float x) { return dppmov<CTRL,0xF,0xF,true>(x); }

template<int PAT>
__device__ __forceinline__ float swz(float x) {
    return __int_as_float(__builtin_amdgcn_ds_swizzle(__float_as_int(x), PAT));
}

// cross-lane fetch functors. xor1/xor2 = quad_perm DPP (cheap, intra-quad).
// xor4/xor8/xor16 = ds_swizzle BitMode (xor<<10 | 0x1F): LDS pipe, overlaps VALU.
struct FX1 { static __device__ __forceinline__ float f(float x){ return dpp1<0xB1>(x); } };
struct FX2 { static __device__ __forceinline__ float f(float x){ return dpp1<0x4E>(x); } };
struct FX4 { static __device__ __forceinline__ float f(float x){ return swz<0x101F>(x); } };
struct FX8 { static __device__ __forceinline__ float f(float x){ return swz<0x201F>(x); } };
struct FX16{ static __device__ __forceinline__ float f(float x){ return swz<0x401F>(x); } };
struct FX32{ static __device__ __forceinline__ float f(float x){ return __shfl_xor(x, 32, 64); } };

__device__ __forceinline__ float rlane(float v, int idx) {
    return __int_as_float(__builtin_amdgcn_readlane(__float_as_int(v), idx));
}

// ---------- gfx950 permlane swap transposes (validated R6/R8/R9/R10) ----------
#if __has_builtin(__builtin_amdgcn_permlane32_swap) && __has_builtin(__builtin_amdgcn_permlane16_swap)
#define HAVE_SWAP 1
__device__ __forceinline__ void plswap32(float &a, float &b) {
    u2v r = __builtin_amdgcn_permlane32_swap(__float_as_uint(a), __float_as_uint(b), false, false);
    a = __uint_as_float(r.x); b = __uint_as_float(r.y);
}
__device__ __forceinline__ void plswap16(float &a, float &b) {
    u2v r = __builtin_amdgcn_permlane16_swap(__float_as_uint(a), __float_as_uint(b), false, false);
    a = __uint_as_float(r.x); b = __uint_as_float(r.y);
}
// one transpose set: lane5<->reg3, lane4<->reg2 (involution, toggles A<->B)
__device__ __forceinline__ void tr_set(float (&s)[16]) {
#pragma unroll
    for (int j = 0; j < 8; ++j) plswap32(s[j], s[j + 8]);
#pragma unroll
    for (int jj = 0; jj < 8; ++jj) {
        const int j = (jj & 3) | ((jj >> 2) << 3);   // 0,1,2,3,8,9,10,11
        plswap16(s[j], s[j + 4]);
    }
}
#else
#define HAVE_SWAP 0
#endif

// wave-wide sum broadcast (validated R3..R10)
__device__ __forceinline__ float wave_reduce(float x) {
    x += dppmov<0x111,0xF,0xF,true >(x);
    x += dppmov<0x112,0xF,0xF,true >(x);
    x += dppmov<0x114,0xF,0xF,true >(x);
    x += dppmov<0x118,0xF,0xF,true >(x);
    x += dppmov<0x142,0xA,0xF,false>(x);
    x += dppmov<0x143,0xC,0xF,false>(x);
    return __int_as_float(__builtin_amdgcn_readlane(__float_as_int(x), 63));
}

// wave-wide product (R9-validated)
__device__ __forceinline__ float wave_product(float x) {
    x *= dpp1<0xB1>(x);
    x *= dpp1<0x4E>(x);
    x *= FX4::f(x);
    x *= FX8::f(x);
    x *= FX16::f(x);
    x *= FX32::f(x);
    return x;
}

// (I - t*J) intra-register pair, applied to both arrays
template<int M>
__device__ __forceinline__ void intra2(float (&sr)[16], float (&si)[16], float t) {
#pragma unroll
    for (int j = 0; j < 16; ++j)
        if ((j & M) == 0) {
            const int k = j | M;
            float r0 = sr[j], r1 = sr[k];
            sr[j] = fmaf(-t, r1, r0);
            sr[k] = fmaf( t, r0, r1);
            float i0 = si[j], i1 = si[k];
            si[j] = fmaf(-t, i1, i0);
            si[k] = fmaf( t, i0, i1);
        }
}

// (I - t*J) cross-lane on both arrays (sign convention validated R1..R10)
template<class PF, int LM>
__device__ __forceinline__ void cross2(float (&sr)[16], float (&si)[16],
                                       float t, int lane) {
    const float sv = (lane & LM) ? t : -t;
#pragma unroll
    for (int j = 0; j < 16; ++j) {
        float pr = PF::f(sr[j]);
        float pi = PF::f(si[j]);
        sr[j] = fmaf(pr, sv, sr[j]);
        si[j] = fmaf(pi, sv, si[j]);
    }
}

template<class PF>
__device__ __forceinline__ float cross_exp2(const float (&sr)[16], const float (&si)[16]) {
    float a = 0.f;
#pragma unroll
    for (int j = 0; j < 16; ++j) {
        a = fmaf(PF::f(sr[j]), sr[j], a);
        a = fmaf(PF::f(si[j]), si[j], a);
    }
    return a;
}

template<int M>
__device__ __forceinline__ float intra_exp2(const float (&sr)[16], const float (&si)[16]) {
    float a = 0.f;
#pragma unroll
    for (int j = 0; j < 16; ++j)
        a += sr[j] * sr[j ^ M] + si[j] * si[j ^ M];
    return a;
}

__global__ __launch_bounds__(256, 2) void qsim_kernel(
    const float* __restrict__ noise,     // (NBATCH, NQ)
    const float* __restrict__ qp,        // (NG, QD, NQ)
    float* __restrict__ out)             // (NBATCH, NG*NQ)
{
    const int wave = threadIdx.x >> 6;
    const int lane = threadIdx.x & 63;
    const int g    = blockIdx.x & 3;                  // block-uniform
    const int b    = (blockIdx.x >> 2) * WPB + wave;  // batch sample per wave

    // ---- weights: lane-parallel sincos once; t = tan, scale2 = prod(c)^2 ----
    float wt, scale2;
    {
        const int widx = (lane < QD * NQ) ? lane : 0;
        float sv, cv;
        __sincosf(0.5f * qp[g * (QD * NQ) + widx], &sv, &cv);
        wt = sv / cv;
        float cvc = (lane < QD * NQ) ? cv : 1.0f;
        float p = wave_product(cvc);
        scale2 = p * p;
    }

    // ---- init: complex product state RX(t)RY(t)|0> (exact, R8/R9-validated) --
    float sr[16], si[16];
    {
        float nc[NQ], ns[NQ];
#pragma unroll
        for (int q = 0; q < NQ; ++q)
            __sincosf(0.5f * noise[b * NQ + q], &ns[q], &nc[q]);

        auto facr = [&](int q, int bit) { return bit ? nc[q]*ns[q] : nc[q]*nc[q]; };
        auto faci = [&](int q, int bit) { return bit ? -nc[q]*ns[q] : -ns[q]*ns[q]; };

        float hr = 1.f, hi = 0.f;
#pragma unroll
        for (int p = 4; p <= 9; ++p) {
            const int q = NQ - 1 - p, bit = (lane >> (p - 4)) & 1;
            float fr = facr(q, bit), fi = faci(q, bit);
            float tr = hr * fr - hi * fi;
            float ti = hr * fi + hi * fr;
            hr = tr; hi = ti;
        }
        float t01r[4], t01i[4], t23r[4], t23i[4];
#pragma unroll
        for (int a = 0; a < 4; ++a) {
            float f9r = facr(9, a & 1), f9i = faci(9, a & 1);
            float f8r = facr(8, (a >> 1) & 1), f8i = faci(8, (a >> 1) & 1);
            t01r[a] = f9r * f8r - f9i * f8i;
            t01i[a] = f9r * f8i + f9i * f8r;
            float f7r = facr(7, a & 1), f7i = faci(7, a & 1);
            float f6r = facr(6, (a >> 1) & 1), f6i = faci(6, (a >> 1) & 1);
            t23r[a] = f7r * f6r - f7i * f6i;
            t23i[a] = f7r * f6i + f7i * f6r;
        }
        float prer[4], prei[4];
#pragma unroll
        for (int a = 0; a < 4; ++a) {
            prer[a] = hr * t01r[a] - hi * t01i[a];
            prei[a] = hr * t01i[a] + hi * t01r[a];
        }
#pragma unroll
        for (int j = 0; j < 16; ++j) {
            sr[j] = prer[j & 3] * t23r[j >> 2] - prei[j & 3] * t23i[j >> 2];
            si[j] = prer[j & 3] * t23i[j >> 2] + prei[j & 3] * t23r[j >> 2];
        }
    }

    // ---- CZ sign masks, both layouts (R9/R10-validated parity decomposition) --
    unsigned aE, aO;
    {
        unsigned parA = (unsigned)(__popc(lane & (lane >> 1)) & 1) << 31;
        aE = parA;                                     // j < 8
        aO = parA ^ ((unsigned)(lane & 1) << 31);      // j >= 8 (pair j3,l0)
    }
    unsigned b00, b10, b01, b11;
    {
        const unsigned l0 = lane & 1, l1 = (lane >> 1) & 1, l2 = (lane >> 2) & 1,
                       l3 = (lane >> 3) & 1, l4 = (lane >> 4) & 1, l5 = (lane >> 5) & 1;
        unsigned parB = ((l4 & l5) ^ (l5 & l0) ^ (l0 & l1) ^ (l1 & l2) ^ (l2 & l3)) << 31;
        b00 = parB;
        b10 = parB ^ (l4 << 31);
        b01 = parB ^ (l3 << 31);
        b11 = parB ^ ((l4 ^ l3) << 31);
    }
    auto czA = [&](float (&vr)[16], float (&vi)[16]) {
#pragma unroll
        for (int j = 0; j < 16; ++j) {
            const bool jp = (__popc(j & (j >> 1)) & 1) != 0;         // compile-time
            const unsigned base = (j & 8) ? aO : aE;
            const unsigned m = jp ? (base ^ 0x80000000u) : base;
            vr[j] = __uint_as_float(__float_as_uint(vr[j]) ^ m);
            vi[j] = __uint_as_float(__float_as_uint(vi[j]) ^ m);
        }
    };
    auto czB = [&](float (&vr)[16], float (&vi)[16]) {
#pragma unroll
        for (int j = 0; j < 16; ++j) {
            const int j0 = j & 1, j1 = (j >> 1) & 1, j2 = (j >> 2) & 1, j3 = (j >> 3) & 1;
            const bool pj = ((j0 & j1) ^ (j2 & j3)) != 0;            // compile-time
            const unsigned base = j1 ? (j2 ? b11 : b10) : (j2 ? b01 : b00);
            const unsigned m = pj ? (base ^ 0x80000000u) : base;
            vr[j] = __uint_as_float(__float_as_uint(vr[j]) ^ m);
            vi[j] = __uint_as_float(__float_as_uint(vi[j]) ^ m);
        }
    };

    // ---- QD layers: 3 x (A-layer, B-layer), one transpose set per layer
    //      (structure validated R10) ----
#if HAVE_SWAP
#pragma unroll 1
    for (int d = 0; d < QD / 2; ++d) {
        float t[2 * NQ];
#pragma unroll
        for (int q = 0; q < 2 * NQ; ++q) t[q] = rlane(wt, 2 * d * NQ + q);

        // ---- A-layer (state in layout A) ----
        intra2<1>(sr, si, t[9]);                 // wire 9 (amp bit 0)
        intra2<2>(sr, si, t[8]);
        intra2<4>(sr, si, t[7]);
        intra2<8>(sr, si, t[6]);
        cross2<FX1, 1>(sr, si, t[5], lane);      // wires 5..2 (lane bits 0..3)
        cross2<FX2, 2>(sr, si, t[4], lane);
        cross2<FX4, 4>(sr, si, t[3], lane);      // LDS-pipe fetch
        cross2<FX8, 8>(sr, si, t[2], lane);      // LDS-pipe fetch
        tr_set(sr); tr_set(si);                  // -> layout B
        intra2<8>(sr, si, t[0]);                 // wire 0 (amp bit 9 = reg 3)
        intra2<4>(sr, si, t[1]);                 // wire 1 (amp bit 8 = reg 2)
        czB(sr, si);

        // ---- B-layer (state in layout B) ----
        intra2<1>(sr, si, t[NQ + 9]);
        intra2<2>(sr, si, t[NQ + 8]);
        intra2<8>(sr, si, t[NQ + 0]);            // wire 0 (reg 3)
        intra2<4>(sr, si, t[NQ + 1]);            // wire 1 (reg 2)
        cross2<FX1, 1>(sr, si, t[NQ + 5], lane); // wires 5..2 unchanged in B
        cross2<FX2, 2>(sr, si, t[NQ + 4], lane);
        cross2<FX4, 4>(sr, si, t[NQ + 3], lane);
        cross2<FX8, 8>(sr, si, t[NQ + 2], lane);
        tr_set(sr); tr_set(si);                  // -> layout A
        intra2<4>(sr, si, t[NQ + 7]);            // wire 7 (amp bit 2 = reg 2)
        intra2<8>(sr, si, t[NQ + 6]);            // wire 6 (amp bit 3 = reg 3)
        czA(sr, si);
    }
#else
#pragma unroll 1
    for (int l = 0; l < QD; ++l) {
        float t[NQ];
#pragma unroll
        for (int q = 0; q < NQ; ++q) t[q] = rlane(wt, l * NQ + q);
        intra2<1>(sr, si, t[9]);
        intra2<2>(sr, si, t[8]);
        intra2<4>(sr, si, t[7]);
        intra2<8>(sr, si, t[6]);
        cross2<FX1, 1>(sr, si, t[5], lane);
        cross2<FX2, 2>(sr, si, t[4], lane);
        cross2<FX4, 4>(sr, si, t[3], lane);
        cross2<FX8, 8>(sr, si, t[2], lane);
        cross2<FX32,32>(sr, si, t[0], lane);
        cross2<FX16,16>(sr, si, t[1], lane);
        czA(sr, si);
    }
#endif

    // ---- expectations <X_q>, scaled by (prod c)^2 (layout A) ----
    float outval = 0.f;
    {
        float e9 = wave_reduce(intra_exp2<1>(sr, si));
        float e8 = wave_reduce(intra_exp2<2>(sr, si));
        float e7 = wave_reduce(intra_exp2<4>(sr, si));
        float e6 = wave_reduce(intra_exp2<8>(sr, si));
        float e5 = wave_reduce(cross_exp2<FX1>(sr, si));
        float e4 = wave_reduce(cross_exp2<FX2>(sr, si));
        float e3 = wave_reduce(cross_exp2<FX4>(sr, si));
        float e2 = wave_reduce(cross_exp2<FX8>(sr, si));
        float e0, e1;
#if HAVE_SWAP
        tr_set(sr); tr_set(si);                  // -> layout B for wires 0,1
        e0 = wave_reduce(intra_exp2<8>(sr, si));
        e1 = wave_reduce(intra_exp2<4>(sr, si));
#else
        e0 = wave_reduce(cross_exp2<FX32>(sr, si));
        e1 = wave_reduce(cross_exp2<FX16>(sr, si));
#endif
        outval = (lane == 0) ? e0 : outval;
        outval = (lane == 1) ? e1 : outval;
        outval = (lane == 2) ? e2 : outval;
        outval = (lane == 3) ? e3 : outval;
        outval = (lane == 4) ? e4 : outval;
        outval = (lane == 5) ? e5 : outval;
        outval = (lane == 6) ? e6 : outval;
        outval = (lane == 7) ? e7 : outval;
        outval = (lane == 8) ? e8 : outval;
        outval = (lane == 9) ? e9 : outval;
    }

    if (lane < NQ)
        out[b * (NG * NQ) + g * NQ + lane] = outval * scale2;
}

extern "C" void kernel_launch(void* const* d_in, const int* in_sizes, int n_in,
                              void* d_out, int out_size, void* d_ws, size_t ws_size,
                              hipStream_t stream) {
    const float* noise = (const float*)d_in[0];   // (1024, 10) float32
    const float* qp    = (const float*)d_in[1];   // (4, 6, 10) float32
    float* out = (float*)d_out;                   // (1024, 40) float32

    const int nblocks = (NBATCH * NG) / WPB;      // 1024 blocks x 4 waves
    qsim_kernel<<<nblocks, 64 * WPB, 0, stream>>>(noise, qp, out);
}

// Round 13
// 83.444 us; speedup vs baseline: 1.0691x; 1.0197x over previous
//
#include <hip/hip_runtime.h>

#define NQ 10
#define NG 4
#define QD 6
#define NBATCH 1024

// 2^10 = 1024 amps; 64 lanes x 16 amps/lane. One WAVE = one REAL COMPONENT
// (re or im) of one circuit: tangent-form layers are real, so re/im evolve
// independently (R10-validated). 8192 waves -> 8/SIMD. Init (complex product
// state) computed ONCE by the even wave; im half shipped via LDS (R7's idea,
// without R7's spill: 16-reg state, no forced min-waves bound). Final
// expectations couple re+im partials via 128 B of LDS (R10-validated).
// Flat index i: bit p (LSB) <-> wire q = 9-p (wire 0 = MSB, PennyLane order).
// Layout A: reg bits 0..3 <- amp bits 0..3, lane bits 0..5 <- amp bits 4..9.
// Layout B: reg2<->lane4, reg3<->lane5 swapped (one tr_set toggles A<->B).
// Cross-lane fetch placement (R12-validated): FX1/FX2 = quad_perm DPP
// (fuses into v_fmac_dpp, ~free), FX4/FX8/FX16 = ds_swizzle (idle LDS pipe),
// FX32 = shfl (bpermute). Alternating A/B layouts halve permlane transposes
// (R10-validated). tan-form rotations + global scale (R9-validated).

typedef unsigned u2v __attribute__((ext_vector_type(2)));

// ---------- DPP helpers ----------
template<int CTRL, int RM, int BM, bool BC>
__device__ __forceinline__ float dppmov(float x) {
    return __int_as_float(__builtin_amdgcn_update_dpp(
        0, __float_as_int(x), CTRL, RM, BM, BC));
}
template<int CTRL>
__device__ __forceinline__ float dpp1(float x) { return dppmov<CTRL,0xF,0xF,true>(x); }

template<int PAT>
__device__ __forceinline__ float swz(float x) {
    return __int_as_float(__builtin_amdgcn_ds_swizzle(__float_as_int(x), PAT));
}

struct FX1 { static __device__ __forceinline__ float f(float x){ return dpp1<0xB1>(x); } };
struct FX2 { static __device__ __forceinline__ float f(float x){ return dpp1<0x4E>(x); } };
struct FX4 { static __device__ __forceinline__ float f(float x){ return swz<0x101F>(x); } };
struct FX8 { static __device__ __forceinline__ float f(float x){ return swz<0x201F>(x); } };
struct FX16{ static __device__ __forceinline__ float f(float x){ return swz<0x401F>(x); } };
struct FX32{ static __device__ __forceinline__ float f(float x){ return __shfl_xor(x, 32, 64); } };

__device__ __forceinline__ float rlane(float v, int idx) {
    return __int_as_float(__builtin_amdgcn_readlane(__float_as_int(v), idx));
}

// ---------- gfx950 permlane swap transposes (validated R6/R8/R9/R10/R12) ----------
#if __has_builtin(__builtin_amdgcn_permlane32_swap) && __has_builtin(__builtin_amdgcn_permlane16_swap)
#define HAVE_SWAP 1
__device__ __forceinline__ void plswap32(float &a, float &b) {
    u2v r = __builtin_amdgcn_permlane32_swap(__float_as_uint(a), __float_as_uint(b), false, false);
    a = __uint_as_float(r.x); b = __uint_as_float(r.y);
}
__device__ __forceinline__ void plswap16(float &a, float &b) {
    u2v r = __builtin_amdgcn_permlane16_swap(__float_as_uint(a), __float_as_uint(b), false, false);
    a = __uint_as_float(r.x); b = __uint_as_float(r.y);
}
// one transpose set: lane5<->reg3, lane4<->reg2 (involution, toggles A<->B)
__device__ __forceinline__ void tr_set(float (&s)[16]) {
#pragma unroll
    for (int j = 0; j < 8; ++j) plswap32(s[j], s[j + 8]);
#pragma unroll
    for (int jj = 0; jj < 8; ++jj) {
        const int j = (jj & 3) | ((jj >> 2) << 3);   // 0,1,2,3,8,9,10,11
        plswap16(s[j], s[j + 4]);
    }
}
#else
#define HAVE_SWAP 0
#endif

// wave-wide sum broadcast (validated R3..R12)
__device__ __forceinline__ float wave_reduce(float x) {
    x += dppmov<0x111,0xF,0xF,true >(x);
    x += dppmov<0x112,0xF,0xF,true >(x);
    x += dppmov<0x114,0xF,0xF,true >(x);
    x += dppmov<0x118,0xF,0xF,true >(x);
    x += dppmov<0x142,0xA,0xF,false>(x);
    x += dppmov<0x143,0xC,0xF,false>(x);
    return __int_as_float(__builtin_amdgcn_readlane(__float_as_int(x), 63));
}

// wave-wide product (R9-validated)
__device__ __forceinline__ float wave_product(float x) {
    x *= dpp1<0xB1>(x);
    x *= dpp1<0x4E>(x);
    x *= FX4::f(x);
    x *= FX8::f(x);
    x *= FX16::f(x);
    x *= FX32::f(x);
    return x;
}

// (I - t*J) intra-register pair (single array)
template<int M>
__device__ __forceinline__ void intra1(float (&s)[16], float t) {
#pragma unroll
    for (int j = 0; j < 16; ++j)
        if ((j & M) == 0) {
            const int k = j | M;
            float v0 = s[j], v1 = s[k];
            s[j] = fmaf(-t, v1, v0);
            s[k] = fmaf( t, v0, v1);
        }
}

// (I - t*J) cross-lane (single array; sign convention validated R1..R12)
template<class PF, int LM>
__device__ __forceinline__ void cross1(float (&s)[16], float t, int lane) {
    const float sv = (lane & LM) ? t : -t;
#pragma unroll
    for (int j = 0; j < 16; ++j)
        s[j] = fmaf(PF::f(s[j]), sv, s[j]);
}

template<class PF>
__device__ __forceinline__ float cross_exp1(const float (&s)[16]) {
    float a = 0.f;
#pragma unroll
    for (int j = 0; j < 16; ++j)
        a = fmaf(PF::f(s[j]), s[j], a);
    return a;
}

template<int M>
__device__ __forceinline__ float intra_exp1(const float (&s)[16]) {
    float a = 0.f;
#pragma unroll
    for (int j = 0; j < 16; ++j)
        a += s[j] * s[j ^ M];
    return a;
}

__global__ __launch_bounds__(256, 2) void qsim_kernel(
    const float* __restrict__ noise,     // (NBATCH, NQ)
    const float* __restrict__ qp,        // (NG, QD, NQ)
    float* __restrict__ out)             // (NBATCH, NG*NQ)
{
    __shared__ float ship[2][1024];      // im half of init state per circuit
    __shared__ float partlds[2][16];     // re-wave expectation partials

    const int wave = threadIdx.x >> 6;
    const int lane = threadIdx.x & 63;
    const int pc   = wave >> 1;                       // circuit within block
    const int comp = wave & 1;                        // 0 = re, 1 = im
    const int g    = blockIdx.x & 3;                  // block-uniform
    const int b    = (blockIdx.x >> 2) * 2 + pc;      // batch index

    // ---- weights: lane-parallel sincos once; t = tan, scale2 = prod(c)^2 ----
    float wt, scale2;
    {
        const int widx = (lane < QD * NQ) ? lane : 0;
        float sv, cv;
        __sincosf(0.5f * qp[g * (QD * NQ) + widx], &sv, &cv);
        wt = sv / cv;
        float cvc = (lane < QD * NQ) ? cv : 1.0f;
        float p = wave_product(cvc);
        scale2 = p * p;
    }

    // ---- init: even wave computes complex product state, ships im via LDS ----
    float s[16];
    if (comp == 0) {
        float nc[NQ], ns[NQ];
#pragma unroll
        for (int q = 0; q < NQ; ++q)
            __sincosf(0.5f * noise[b * NQ + q], &ns[q], &nc[q]);

        auto facr = [&](int q, int bit) { return bit ? nc[q]*ns[q] : nc[q]*nc[q]; };
        auto faci = [&](int q, int bit) { return bit ? -nc[q]*ns[q] : -ns[q]*ns[q]; };

        float hr = 1.f, hi = 0.f;
#pragma unroll
        for (int p = 4; p <= 9; ++p) {
            const int q = NQ - 1 - p, bit = (lane >> (p - 4)) & 1;
            float fr = facr(q, bit), fi = faci(q, bit);
            float tr = hr * fr - hi * fi;
            float ti = hr * fi + hi * fr;
            hr = tr; hi = ti;
        }
        float t01r[4], t01i[4], t23r[4], t23i[4];
#pragma unroll
        for (int a = 0; a < 4; ++a) {
            float f9r = facr(9, a & 1), f9i = faci(9, a & 1);
            float f8r = facr(8, (a >> 1) & 1), f8i = faci(8, (a >> 1) & 1);
            t01r[a] = f9r * f8r - f9i * f8i;
            t01i[a] = f9r * f8i + f9i * f8r;
            float f7r = facr(7, a & 1), f7i = faci(7, a & 1);
            float f6r = facr(6, (a >> 1) & 1), f6i = faci(6, (a >> 1) & 1);
            t23r[a] = f7r * f6r - f7i * f6i;
            t23i[a] = f7r * f6i + f7i * f6r;
        }
        float prer[4], prei[4];
#pragma unroll
        for (int a = 0; a < 4; ++a) {
            prer[a] = hr * t01r[a] - hi * t01i[a];
            prei[a] = hr * t01i[a] + hi * t01r[a];
        }
#pragma unroll
        for (int j = 0; j < 16; ++j) {
            s[j] = prer[j & 3] * t23r[j >> 2] - prei[j & 3] * t23i[j >> 2];
            float ii = prer[j & 3] * t23i[j >> 2] + prei[j & 3] * t23r[j >> 2];
            ship[pc][j * 64 + lane] = ii;   // conflict-free (stride-1 per lane)
        }
    }
    __syncthreads();
    if (comp == 1) {
#pragma unroll
        for (int j = 0; j < 16; ++j) s[j] = ship[pc][j * 64 + lane];
    }

    // ---- CZ sign masks, both layouts (R9/R10/R12-validated) ----
    unsigned aE, aO;
    {
        unsigned parA = (unsigned)(__popc(lane & (lane >> 1)) & 1) << 31;
        aE = parA;                                     // j < 8
        aO = parA ^ ((unsigned)(lane & 1) << 31);      // j >= 8 (pair j3,l0)
    }
    unsigned b00, b10, b01, b11;
    {
        const unsigned l0 = lane & 1, l1 = (lane >> 1) & 1, l2 = (lane >> 2) & 1,
                       l3 = (lane >> 3) & 1, l4 = (lane >> 4) & 1, l5 = (lane >> 5) & 1;
        unsigned parB = ((l4 & l5) ^ (l5 & l0) ^ (l0 & l1) ^ (l1 & l2) ^ (l2 & l3)) << 31;
        b00 = parB;
        b10 = parB ^ (l4 << 31);
        b01 = parB ^ (l3 << 31);
        b11 = parB ^ ((l4 ^ l3) << 31);
    }
    auto czA = [&](float (&v)[16]) {
#pragma unroll
        for (int j = 0; j < 16; ++j) {
            const bool jp = (__popc(j & (j >> 1)) & 1) != 0;         // compile-time
            const unsigned base = (j & 8) ? aO : aE;
            const unsigned m = jp ? (base ^ 0x80000000u) : base;
            v[j] = __uint_as_float(__float_as_uint(v[j]) ^ m);
        }
    };
    auto czB = [&](float (&v)[16]) {
#pragma unroll
        for (int j = 0; j < 16; ++j) {
            const int j0 = j & 1, j1 = (j >> 1) & 1, j2 = (j >> 2) & 1, j3 = (j >> 3) & 1;
            const bool pj = ((j0 & j1) ^ (j2 & j3)) != 0;            // compile-time
            const unsigned base = j1 ? (j2 ? b11 : b10) : (j2 ? b01 : b00);
            const unsigned m = pj ? (base ^ 0x80000000u) : base;
            v[j] = __uint_as_float(__float_as_uint(v[j]) ^ m);
        }
    };

    // ---- QD layers: 3 x (A-layer, B-layer), one transpose set per layer
    //      (structure R10-validated; swizzle placement R12-validated) ----
#if HAVE_SWAP
#pragma unroll 1
    for (int d = 0; d < QD / 2; ++d) {
        float t[2 * NQ];
#pragma unroll
        for (int q = 0; q < 2 * NQ; ++q) t[q] = rlane(wt, 2 * d * NQ + q);

        // ---- A-layer (state in layout A) ----
        intra1<1>(s, t[9]);                      // wire 9 (amp bit 0)
        intra1<2>(s, t[8]);
        intra1<4>(s, t[7]);
        intra1<8>(s, t[6]);
        cross1<FX1, 1>(s, t[5], lane);           // wires 5..2 (lane bits 0..3)
        cross1<FX2, 2>(s, t[4], lane);
        cross1<FX4, 4>(s, t[3], lane);           // LDS-pipe fetch
        cross1<FX8, 8>(s, t[2], lane);           // LDS-pipe fetch
        tr_set(s);                               // -> layout B
        intra1<8>(s, t[0]);                      // wire 0 (amp bit 9 = reg 3)
        intra1<4>(s, t[1]);                      // wire 1 (amp bit 8 = reg 2)
        czB(s);

        // ---- B-layer (state in layout B) ----
        intra1<1>(s, t[NQ + 9]);
        intra1<2>(s, t[NQ + 8]);
        intra1<8>(s, t[NQ + 0]);                 // wire 0 (reg 3)
        intra1<4>(s, t[NQ + 1]);                 // wire 1 (reg 2)
        cross1<FX1, 1>(s, t[NQ + 5], lane);      // wires 5..2 unchanged in B
        cross1<FX2, 2>(s, t[NQ + 4], lane);
        cross1<FX4, 4>(s, t[NQ + 3], lane);
        cross1<FX8, 8>(s, t[NQ + 2], lane);
        tr_set(s);                               // -> layout A
        intra1<4>(s, t[NQ + 7]);                 // wire 7 (amp bit 2 = reg 2)
        intra1<8>(s, t[NQ + 6]);                 // wire 6 (amp bit 3 = reg 3)
        czA(s);
    }
#else
#pragma unroll 1
    for (int l = 0; l < QD; ++l) {
        float t[NQ];
#pragma unroll
        for (int q = 0; q < NQ; ++q) t[q] = rlane(wt, l * NQ + q);
        intra1<1>(s, t[9]);
        intra1<2>(s, t[8]);
        intra1<4>(s, t[7]);
        intra1<8>(s, t[6]);
        cross1<FX1, 1>(s, t[5], lane);
        cross1<FX2, 2>(s, t[4], lane);
        cross1<FX4, 4>(s, t[3], lane);
        cross1<FX8, 8>(s, t[2], lane);
        cross1<FX32,32>(s, t[0], lane);
        cross1<FX16,16>(s, t[1], lane);
        czA(s);
    }
#endif

    // ---- expectations: this component's partial sums (layout A) ----
    float myp = 0.f;
    {
        float e9 = wave_reduce(intra_exp1<1>(s));
        float e8 = wave_reduce(intra_exp1<2>(s));
        float e7 = wave_reduce(intra_exp1<4>(s));
        float e6 = wave_reduce(intra_exp1<8>(s));
        float e5 = wave_reduce(cross_exp1<FX1>(s));
        float e4 = wave_reduce(cross_exp1<FX2>(s));
        float e3 = wave_reduce(cross_exp1<FX4>(s));
        float e2 = wave_reduce(cross_exp1<FX8>(s));
        float e0, e1;
#if HAVE_SWAP
        tr_set(s);                               // -> layout B for wires 0,1
        e0 = wave_reduce(intra_exp1<8>(s));
        e1 = wave_reduce(intra_exp1<4>(s));
#else
        e0 = wave_reduce(cross_exp1<FX32>(s));
        e1 = wave_reduce(cross_exp1<FX16>(s));
#endif
        myp = (lane == 0) ? e0 : myp;
        myp = (lane == 1) ? e1 : myp;
        myp = (lane == 2) ? e2 : myp;
        myp = (lane == 3) ? e3 : myp;
        myp = (lane == 4) ? e4 : myp;
        myp = (lane == 5) ? e5 : myp;
        myp = (lane == 6) ? e6 : myp;
        myp = (lane == 7) ? e7 : myp;
        myp = (lane == 8) ? e8 : myp;
        myp = (lane == 9) ? e9 : myp;
    }

    // ---- couple re+im partials via LDS; im wave stores (R10-validated) ----
    if (comp == 0 && lane < NQ) partlds[pc][lane] = myp;
    __syncthreads();
    if (comp == 1 && lane < NQ)
        out[b * (NG * NQ) + g * NQ + lane] = (myp + partlds[pc][lane]) * scale2;
}

extern "C" void kernel_launch(void* const* d_in, const int* in_sizes, int n_in,
                              void* d_out, int out_size, void* d_ws, size_t ws_size,
                              hipStream_t stream) {
    const float* noise = (const float*)d_in[0];   // (1024, 10) float32
    const float* qp    = (const float*)d_in[1];   // (4, 6, 10) float32
    float* out = (float*)d_out;                   // (1024, 40) float32

    const int nblocks = (NBATCH * NG) / 2;        // 2048 blocks x 4 waves
    qsim_kernel<<<nblocks, 256, 0, stream>>>(noise, qp, out);
}

// Round 14
// 81.976 us; speedup vs baseline: 1.0883x; 1.0179x over previous
//
#include <hip/hip_runtime.h>

#define NQ 10
#define NG 4
#define QD 6
#define NBATCH 1024

// 2^10 = 1024 amps; 64 lanes x 16 amps/lane. One WAVE = one REAL COMPONENT
// (re or im) of one circuit (tangent-form layers are real; R10/R13-validated).
// 8192 waves -> 8/SIMD. Init computed once by the even wave, im shipped via
// LDS (R13-validated). Expectations couple re+im partials via 128 B LDS.
// Flat index i: bit p (LSB) <-> wire q = 9-p (wire 0 = MSB, PennyLane order).
// Layout A ONLY: reg bits 0..3 <- amp bits 0..3, lane bits 0..5 <- amp 4..9.
// R14: permlane transposes deleted. Fetch placement by measured pipe cost:
//   xor1/xor2  = quad_perm DPP (fuses into v_fmac_dpp, ~free)     [VALU]
//   xor4/8/16  = ds_swizzle BitMode (R12-validated win)           [LDS pipe]
//   xor32      = __shfl_xor -> ds_bpermute (addr hoisted)         [LDS pipe]
// tan-form rotations + global scale (R9), CZ sign-bit xor layout-A masks.

typedef unsigned u2v __attribute__((ext_vector_type(2)));

// ---------- DPP helpers ----------
template<int CTRL, int RM, int BM, bool BC>
__device__ __forceinline__ float dppmov(float x) {
    return __int_as_float(__builtin_amdgcn_update_dpp(
        0, __float_as_int(x), CTRL, RM, BM, BC));
}
template<int CTRL>
__device__ __forceinline__ float dpp1(float x) { return dppmov<CTRL,0xF,0xF,true>(x); }

template<int PAT>
__device__ __forceinline__ float swz(float x) {
    return __int_as_float(__builtin_amdgcn_ds_swizzle(__float_as_int(x), PAT));
}

struct FX1 { static __device__ __forceinline__ float f(float x){ return dpp1<0xB1>(x); } };
struct FX2 { static __device__ __forceinline__ float f(float x){ return dpp1<0x4E>(x); } };
struct FX4 { static __device__ __forceinline__ float f(float x){ return swz<0x101F>(x); } };
struct FX8 { static __device__ __forceinline__ float f(float x){ return swz<0x201F>(x); } };
struct FX16{ static __device__ __forceinline__ float f(float x){ return swz<0x401F>(x); } };
struct FX32{ static __device__ __forceinline__ float f(float x){ return __shfl_xor(x, 32, 64); } };

__device__ __forceinline__ float rlane(float v, int idx) {
    return __int_as_float(__builtin_amdgcn_readlane(__float_as_int(v), idx));
}

// wave-wide sum broadcast (validated R3..R13)
__device__ __forceinline__ float wave_reduce(float x) {
    x += dppmov<0x111,0xF,0xF,true >(x);
    x += dppmov<0x112,0xF,0xF,true >(x);
    x += dppmov<0x114,0xF,0xF,true >(x);
    x += dppmov<0x118,0xF,0xF,true >(x);
    x += dppmov<0x142,0xA,0xF,false>(x);
    x += dppmov<0x143,0xC,0xF,false>(x);
    return __int_as_float(__builtin_amdgcn_readlane(__float_as_int(x), 63));
}

// wave-wide product (R9-validated)
__device__ __forceinline__ float wave_product(float x) {
    x *= dpp1<0xB1>(x);
    x *= dpp1<0x4E>(x);
    x *= FX4::f(x);
    x *= FX8::f(x);
    x *= FX16::f(x);
    x *= FX32::f(x);
    return x;
}

// (I - t*J) intra-register pair (R9-validated)
template<int M>
__device__ __forceinline__ void intra1(float (&s)[16], float t) {
#pragma unroll
    for (int j = 0; j < 16; ++j)
        if ((j & M) == 0) {
            const int k = j | M;
            float v0 = s[j], v1 = s[k];
            s[j] = fmaf(-t, v1, v0);
            s[k] = fmaf( t, v0, v1);
        }
}

// (I - t*J) cross-lane (sign convention validated R1..R13)
template<class PF, int LM>
__device__ __forceinline__ void cross1(float (&s)[16], float t, int lane) {
    const float sv = (lane & LM) ? t : -t;
#pragma unroll
    for (int j = 0; j < 16; ++j)
        s[j] = fmaf(PF::f(s[j]), sv, s[j]);
}

template<class PF>
__device__ __forceinline__ float cross_exp1(const float (&s)[16]) {
    float a = 0.f;
#pragma unroll
    for (int j = 0; j < 16; ++j)
        a = fmaf(PF::f(s[j]), s[j], a);
    return a;
}

template<int M>
__device__ __forceinline__ float intra_exp1(const float (&s)[16]) {
    float a = 0.f;
#pragma unroll
    for (int j = 0; j < 16; ++j)
        a += s[j] * s[j ^ M];
    return a;
}

__global__ __launch_bounds__(256, 2) void qsim_kernel(
    const float* __restrict__ noise,     // (NBATCH, NQ)
    const float* __restrict__ qp,        // (NG, QD, NQ)
    float* __restrict__ out)             // (NBATCH, NG*NQ)
{
    __shared__ float ship[2][1024];      // im half of init state per circuit
    __shared__ float partlds[2][16];     // re-wave expectation partials

    const int wave = threadIdx.x >> 6;
    const int lane = threadIdx.x & 63;
    const int pc   = wave >> 1;                       // circuit within block
    const int comp = wave & 1;                        // 0 = re, 1 = im
    const int g    = blockIdx.x & 3;                  // block-uniform
    const int b    = (blockIdx.x >> 2) * 2 + pc;      // batch index

    // ---- weights: lane-parallel sincos once; t = tan, scale2 = prod(c)^2 ----
    float wt, scale2;
    {
        const int widx = (lane < QD * NQ) ? lane : 0;
        float sv, cv;
        __sincosf(0.5f * qp[g * (QD * NQ) + widx], &sv, &cv);
        wt = sv / cv;
        float cvc = (lane < QD * NQ) ? cv : 1.0f;
        float p = wave_product(cvc);
        scale2 = p * p;
    }

    // ---- init: even wave computes complex product state, ships im via LDS ----
    float s[16];
    if (comp == 0) {
        float nc[NQ], ns[NQ];
#pragma unroll
        for (int q = 0; q < NQ; ++q)
            __sincosf(0.5f * noise[b * NQ + q], &ns[q], &nc[q]);

        auto facr = [&](int q, int bit) { return bit ? nc[q]*ns[q] : nc[q]*nc[q]; };
        auto faci = [&](int q, int bit) { return bit ? -nc[q]*ns[q] : -ns[q]*ns[q]; };

        float hr = 1.f, hi = 0.f;
#pragma unroll
        for (int p = 4; p <= 9; ++p) {
            const int q = NQ - 1 - p, bit = (lane >> (p - 4)) & 1;
            float fr = facr(q, bit), fi = faci(q, bit);
            float tr = hr * fr - hi * fi;
            float ti = hr * fi + hi * fr;
            hr = tr; hi = ti;
        }
        float t01r[4], t01i[4], t23r[4], t23i[4];
#pragma unroll
        for (int a = 0; a < 4; ++a) {
            float f9r = facr(9, a & 1), f9i = faci(9, a & 1);
            float f8r = facr(8, (a >> 1) & 1), f8i = faci(8, (a >> 1) & 1);
            t01r[a] = f9r * f8r - f9i * f8i;
            t01i[a] = f9r * f8i + f9i * f8r;
            float f7r = facr(7, a & 1), f7i = faci(7, a & 1);
            float f6r = facr(6, (a >> 1) & 1), f6i = faci(6, (a >> 1) & 1);
            t23r[a] = f7r * f6r - f7i * f6i;
            t23i[a] = f7r * f6i + f7i * f6r;
        }
        float prer[4], prei[4];
#pragma unroll
        for (int a = 0; a < 4; ++a) {
            prer[a] = hr * t01r[a] - hi * t01i[a];
            prei[a] = hr * t01i[a] + hi * t01r[a];
        }
#pragma unroll
        for (int j = 0; j < 16; ++j) {
            s[j] = prer[j & 3] * t23r[j >> 2] - prei[j & 3] * t23i[j >> 2];
            float ii = prer[j & 3] * t23i[j >> 2] + prei[j & 3] * t23r[j >> 2];
            ship[pc][j * 64 + lane] = ii;   // conflict-free (stride-1 per lane)
        }
    }
    __syncthreads();
    if (comp == 1) {
#pragma unroll
        for (int j = 0; j < 16; ++j) s[j] = ship[pc][j * 64 + lane];
    }

    // ---- CZ sign masks, layout A (R9/R12-validated parity decomposition) ----
    unsigned aE, aO;
    {
        unsigned parA = (unsigned)(__popc(lane & (lane >> 1)) & 1) << 31;
        aE = parA;                                     // j < 8
        aO = parA ^ ((unsigned)(lane & 1) << 31);      // j >= 8 (pair j3,l0)
    }
    auto czA = [&](float (&v)[16]) {
#pragma unroll
        for (int j = 0; j < 16; ++j) {
            const bool jp = (__popc(j & (j >> 1)) & 1) != 0;         // compile-time
            const unsigned base = (j & 8) ? aO : aE;
            const unsigned m = jp ? (base ^ 0x80000000u) : base;
            v[j] = __uint_as_float(__float_as_uint(v[j]) ^ m);
        }
    };

    // ---- QD layers: layout A throughout; LDS-pipe fetches for xor4..32 ----
#pragma unroll 1
    for (int l = 0; l < QD; ++l) {
        float t[NQ];
#pragma unroll
        for (int q = 0; q < NQ; ++q) t[q] = rlane(wt, l * NQ + q);

        // LDS-pipe wires first so swizzles issue early; RY on distinct wires
        // commute exactly, so order is free.
        cross1<FX4, 4>(s, t[3], lane);           // wire 3 (lane bit 2)  [LDS]
        cross1<FX8, 8>(s, t[2], lane);           // wire 2 (lane bit 3)  [LDS]
        cross1<FX16,16>(s, t[1], lane);          // wire 1 (lane bit 4)  [LDS]
        cross1<FX32,32>(s, t[0], lane);          // wire 0 (lane bit 5)  [LDS]
        intra1<1>(s, t[9]);                      // wires 9..6 (reg bits)
        intra1<2>(s, t[8]);
        intra1<4>(s, t[7]);
        intra1<8>(s, t[6]);
        cross1<FX1, 1>(s, t[5], lane);           // wire 5 (lane bit 0)  [DPP]
        cross1<FX2, 2>(s, t[4], lane);           // wire 4 (lane bit 1)  [DPP]
        czA(s);
    }

    // ---- expectations: this component's partial sums ----
    float myp = 0.f;
    {
        float e9 = wave_reduce(intra_exp1<1>(s));
        float e8 = wave_reduce(intra_exp1<2>(s));
        float e7 = wave_reduce(intra_exp1<4>(s));
        float e6 = wave_reduce(intra_exp1<8>(s));
        float e5 = wave_reduce(cross_exp1<FX1>(s));
        float e4 = wave_reduce(cross_exp1<FX2>(s));
        float e3 = wave_reduce(cross_exp1<FX4>(s));
        float e2 = wave_reduce(cross_exp1<FX8>(s));
        float e1 = wave_reduce(cross_exp1<FX16>(s));
        float e0 = wave_reduce(cross_exp1<FX32>(s));
        myp = (lane == 0) ? e0 : myp;
        myp = (lane == 1) ? e1 : myp;
        myp = (lane == 2) ? e2 : myp;
        myp = (lane == 3) ? e3 : myp;
        myp = (lane == 4) ? e4 : myp;
        myp = (lane == 5) ? e5 : myp;
        myp = (lane == 6) ? e6 : myp;
        myp = (lane == 7) ? e7 : myp;
        myp = (lane == 8) ? e8 : myp;
        myp = (lane == 9) ? e9 : myp;
    }

    // ---- couple re+im partials via LDS; im wave stores (R13-validated) ----
    if (comp == 0 && lane < NQ) partlds[pc][lane] = myp;
    __syncthreads();
    if (comp == 1 && lane < NQ)
        out[b * (NG * NQ) + g * NQ + lane] = (myp + partlds[pc][lane]) * scale2;
}

extern "C" void kernel_launch(void* const* d_in, const int* in_sizes, int n_in,
                              void* d_out, int out_size, void* d_ws, size_t ws_size,
                              hipStream_t stream) {
    const float* noise = (const float*)d_in[0];   // (1024, 10) float32
    const float* qp    = (const float*)d_in[1];   // (4, 6, 10) float32
    float* out = (float*)d_out;                   // (1024, 40) float32

    const int nblocks = (NBATCH * NG) / 2;        // 2048 blocks x 4 waves
    qsim_kernel<<<nblocks, 256, 0, stream>>>(noise, qp, out);
}